// Round 7
// baseline (600.599 us; speedup 1.0000x reference)
//
#include <hip/hip_runtime.h>
#include <math.h>

#define NN 768
#define CSn 384
#define CZn 128
#define Hn 12
#define CONCATn 2112

// ---------------------------------------------------------------------------
// K1: linG[768][1152] = s @ [Wq|Wkv|Wqp|Wkvp] + bias.  Grid (48 rt, 18 ct).
// ---------------------------------------------------------------------------
__global__ __launch_bounds__(256, 4) void proj_gemm(
    const float* __restrict__ s,
    const float* __restrict__ Wq, const float* __restrict__ bq,
    const float* __restrict__ Wkv, const float* __restrict__ bkv,
    const float* __restrict__ Wqp, const float* __restrict__ bqp,
    const float* __restrict__ Wkvp, const float* __restrict__ bkvp,
    float* __restrict__ linG)
{
    const int rt = blockIdx.x;      // 16-row tile
    const int ct = blockIdx.y;      // 64-col tile
    const int t = threadIdx.x;
    const int r0 = rt * 16;
    __shared__ float sl[16 * 388];
    for (int x4 = t; x4 < 1536; x4 += 256) {
        const int r = x4 / 96, c4 = x4 % 96;
        *(float4*)&sl[r * 388 + c4 * 4] = *(const float4*)(s + (size_t)(r0 + r) * CSn + c4 * 4);
    }
    __syncthreads();
    const int c = t & 63, rq = t >> 6;
    const int col = ct * 64 + c;
    const float* Wp; int fout; float bias;
    if (col < 192)      { Wp = Wq + col;         fout = 192; bias = bq[col]; }
    else if (col < 576) { Wp = Wkv + (col-192);  fout = 384; bias = bkv[col-192]; }
    else if (col < 720) { Wp = Wqp + (col-576);  fout = 144; bias = bqp[col-576]; }
    else                { Wp = Wkvp + (col-720); fout = 432; bias = bkvp[col-720]; }
    float a0=bias, a1=bias, a2=bias, a3=bias;
    const float* s0 = sl + (rq*4+0)*388;
    const float* s1 = sl + (rq*4+1)*388;
    const float* s2 = sl + (rq*4+2)*388;
    const float* s3 = sl + (rq*4+3)*388;
    #pragma unroll 4
    for (int kk = 0; kk < 384; ++kk) {
        const float wv = *Wp; Wp += fout;
        a0 += s0[kk]*wv; a1 += s1[kk]*wv; a2 += s2[kk]*wv; a3 += s3[kk]*wv;
    }
    float* lr = linG + (size_t)(r0 + rq*4) * 1152 + col;
    lr[0] = a0; lr[1152] = a1; lr[2*1152] = a2; lr[3*1152] = a3;
}

// ---------------------------------------------------------------------------
// K2: scatter linG -> q [N][192], kT [192][768], v [N][192], qp [N][144],
//     kpT [144][768], vp [N][288]; block 0 builds WbT[12][128].
// ---------------------------------------------------------------------------
__global__ __launch_bounds__(256) void scatter_kernel(
    const float* __restrict__ linG, const float* __restrict__ rot, const float* __restrict__ trans,
    const float* __restrict__ Wb,
    float* __restrict__ q, float* __restrict__ kT, float* __restrict__ v,
    float* __restrict__ qp, float* __restrict__ kpT, float* __restrict__ vp,
    float* __restrict__ WbT)
{
    const int i = blockIdx.x, t = threadIdx.x;
    const float* lr = linG + (size_t)i * 1152;
    if (t < 192) q[(size_t)i*192 + t] = lr[t];
    for (int tt = t; tt < 384; tt += 256) {
        const int h = tt >> 5, cc = tt & 31;
        const float val = lr[192 + tt];
        if (cc < 16) kT[(size_t)(h*16 + cc)*NN + i] = val;
        else         v[(size_t)i*192 + h*16 + (cc-16)] = val;
    }
    const float R0 = rot[i*9+0], R1 = rot[i*9+1], R2 = rot[i*9+2];
    const float R3 = rot[i*9+3], R4 = rot[i*9+4], R5 = rot[i*9+5];
    const float R6 = rot[i*9+6], R7 = rot[i*9+7], R8 = rot[i*9+8];
    const float T0 = trans[i*3+0], T1 = trans[i*3+1], T2 = trans[i*3+2];
    if (t < 48) {
        const float px = lr[576 + t], py = lr[576 + 48 + t], pz = lr[576 + 96 + t];
        float* d = qp + (size_t)i*144 + t*3;
        d[0] = R0*px + R1*py + R2*pz + T0;
        d[1] = R3*px + R4*py + R5*pz + T1;
        d[2] = R6*px + R7*py + R8*pz + T2;
    }
    if (t < 144) {
        const float px = lr[720 + t], py = lr[720 + 144 + t], pz = lr[720 + 288 + t];
        const float gx = R0*px + R1*py + R2*pz + T0;
        const float gy = R3*px + R4*py + R5*pz + T1;
        const float gz = R6*px + R7*py + R8*pz + T2;
        const int h = t / 12, pp = t % 12;
        if (pp < 4) {
            float* d = kpT + (size_t)(h*12 + pp*3)*NN + i;
            d[0] = gx; d[NN] = gy; d[2*NN] = gz;
        } else {
            float* d = vp + (size_t)i*288 + ((h*8) + (pp-4))*3;
            d[0] = gx; d[1] = gy; d[2] = gz;
        }
    }
    if (i == 0) for (int x = t; x < 1536; x += 256) WbT[x] = Wb[(x & 127)*12 + (x >> 7)];
}

// ---------------------------------------------------------------------------
// K3: biasg = S_B*(z@Wb + bb) -> bG[i][h][j] (28 MB).  Grid (12 jt, 768 i).
// Pure z-streaming GEMV: quad lanes split channels (2x line amplification),
// 2 shuffles reduce, lane g writes heads 3g..3g+2.  (256,4): ~64 VGPR for MLP.
// ---------------------------------------------------------------------------
__global__ __launch_bounds__(256, 4) void biasg_kernel(
    const float* __restrict__ z, const float* __restrict__ WbT,
    const float* __restrict__ bb, float* __restrict__ bG)
{
    const int jt = blockIdx.x, i = blockIdx.y, t = threadIdx.x;
    const int jl = t >> 2, g = t & 3;
    const int j = jt * 64 + jl;
    const float* zr = z + ((size_t)i * NN + j) * CZn + g * 4;
    float bh[12];
    #pragma unroll
    for (int h = 0; h < 12; ++h) bh[h] = 0.f;
    #pragma unroll
    for (int u = 0; u < 8; ++u) {
        const float4 zv = *(const float4*)(zr + u * 16);
        const float* wb = WbT + u*16 + g*4;
        #pragma unroll
        for (int h = 0; h < 12; ++h) {
            const float4 wv = *(const float4*)(wb + h * 128);
            bh[h] += zv.x*wv.x + zv.y*wv.y + zv.z*wv.z + zv.w*wv.w;
        }
    }
    #pragma unroll
    for (int h = 0; h < 12; ++h) {
        bh[h] += __shfl_xor(bh[h], 1);
        bh[h] += __shfl_xor(bh[h], 2);
    }
    float bsel[3];
    #pragma unroll
    for (int hh = 0; hh < 3; ++hh) {
        const float v01 = (g & 1) ? bh[3+hh] : bh[0+hh];
        const float v23 = (g & 1) ? bh[9+hh] : bh[6+hh];
        bsel[hh] = (g & 2) ? v23 : v01;
    }
    float* bgr = bG + (size_t)i * (Hn*NN) + j;
    #pragma unroll
    for (int hh = 0; hh < 3; ++hh) {
        const int h = 3*g + hh;
        bgr[(size_t)h * NN] = 0.5773502691896258f * (bsel[hh] + bb[h]);
    }
}

// ---------------------------------------------------------------------------
// K4: fused logits+softmax.  Grid (768 i); wave w owns heads 3w..3w+2,
// lane l spans j (12 strips of 64).  kT/kpT/bG/mask reads lane-coalesced;
// q/qp/coef staged in LDS.  Writes aG (may alias bG: element-wise owner-safe).
// ---------------------------------------------------------------------------
__global__ __launch_bounds__(256, 3) void lgsm_kernel(
    const float* __restrict__ mask,
    const float* __restrict__ q, const float* __restrict__ qp,
    const float* __restrict__ kT, const float* __restrict__ kpT,
    const float* __restrict__ bG, const float* __restrict__ head_w,
    float* __restrict__ aG)
{
    const int i = blockIdx.x, t = threadIdx.x;
    const int w = t >> 6, l = t & 63;
    __shared__ float qs[192], qps[144], coefS[12];
    if (t < 192) qs[t] = q[(size_t)i*192 + t];
    if (t < 144) qps[t] = qp[(size_t)i*144 + t];
    if (t < 12) coefS[t] = -0.5f * 0.1360827634879543f * log1pf(expf(head_w[t]));
    __syncthreads();
    const float mi = mask[i];

    #pragma unroll 1
    for (int hh = 0; hh < 3; ++hh) {
        const int h = w*3 + hh;
        float qreg[16], qpreg[12];
        #pragma unroll
        for (int c = 0; c < 16; ++c) qreg[c] = qs[h*16 + c];
        #pragma unroll
        for (int e = 0; e < 12; ++e) qpreg[e] = qps[h*12 + e];
        const float coef = coefS[h];
        const float* kb  = kT  + (size_t)(h*16)*NN + l;
        const float* kpb = kpT + (size_t)(h*12)*NN + l;
        const float* bgb = bG + (size_t)i*(Hn*NN) + (size_t)h*NN + l;
        float e[12];
        #pragma unroll
        for (int u = 0; u < 12; ++u) {
            const int jo = u * 64;
            float qk = 0.f;
            #pragma unroll
            for (int c = 0; c < 16; ++c) qk += qreg[c] * kb[(size_t)c*NN + jo];
            float d2s = 0.f;
            #pragma unroll
            for (int ee = 0; ee < 12; ++ee) {
                const float d = qpreg[ee] - kpb[(size_t)ee*NN + jo];
                d2s += d * d;
            }
            const float mterm = 100000.0f * (mi * mask[l + jo] - 1.0f);
            e[u] = 0.14433756729740643f*qk + bgb[jo] + coef*d2s + mterm;
        }
        float m = -1e30f;
        #pragma unroll
        for (int u = 0; u < 12; ++u) m = fmaxf(m, e[u]);
        #pragma unroll
        for (int off = 32; off > 0; off >>= 1) m = fmaxf(m, __shfl_xor(m, off));
        float ssum = 0.f;
        #pragma unroll
        for (int u = 0; u < 12; ++u) { e[u] = expf(e[u] - m); ssum += e[u]; }
        #pragma unroll
        for (int off = 32; off > 0; off >>= 1) ssum += __shfl_xor(ssum, off);
        const float inv = 1.0f / ssum;
        float* aw = aG + (size_t)i*(Hn*NN) + (size_t)h*NN + l;
        #pragma unroll
        for (int u = 0; u < 12; ++u) aw[u*64] = e[u] * inv;
    }
}

// ---------------------------------------------------------------------------
// K5: o (192) + o_pt (288) + frame-invert + norms.  Grid (768 i, 2 half).
// ---------------------------------------------------------------------------
__global__ __launch_bounds__(256, 4) void opt_kernel(
    const float* __restrict__ aG, const float* __restrict__ v, const float* __restrict__ vp,
    const float* __restrict__ rot, const float* __restrict__ trans,
    float* __restrict__ cat)
{
    const int i = blockIdx.x, half = blockIdx.y, t = threadIdx.x;
    __shared__ float pts[240];
    if (t < 240) {
        const int o = half*240 + t;
        float acc = 0.f;
        if (o < 192) {
            const float* ar = aG + ((size_t)i*Hn + (o >> 4))*NN;
            const float* src = v + o;
            for (int jb = 0; jb < NN; jb += 8) {
                const float4 A0 = *(const float4*)(ar + jb);
                const float4 A1 = *(const float4*)(ar + jb + 4);
                acc += A0.x*src[(size_t)(jb+0)*192] + A0.y*src[(size_t)(jb+1)*192]
                     + A0.z*src[(size_t)(jb+2)*192] + A0.w*src[(size_t)(jb+3)*192]
                     + A1.x*src[(size_t)(jb+4)*192] + A1.y*src[(size_t)(jb+5)*192]
                     + A1.z*src[(size_t)(jb+6)*192] + A1.w*src[(size_t)(jb+7)*192];
            }
            cat[(size_t)i*CONCATn + o] = acc;
        } else {
            const int p = o - 192;
            const float* ar = aG + ((size_t)i*Hn + (p / 24))*NN;
            const float* src = vp + p;
            for (int jb = 0; jb < NN; jb += 8) {
                const float4 A0 = *(const float4*)(ar + jb);
                const float4 A1 = *(const float4*)(ar + jb + 4);
                acc += A0.x*src[(size_t)(jb+0)*288] + A0.y*src[(size_t)(jb+1)*288]
                     + A0.z*src[(size_t)(jb+2)*288] + A0.w*src[(size_t)(jb+3)*288]
                     + A1.x*src[(size_t)(jb+4)*288] + A1.y*src[(size_t)(jb+5)*288]
                     + A1.z*src[(size_t)(jb+6)*288] + A1.w*src[(size_t)(jb+7)*288];
            }
            pts[half ? t : (t - 192)] = acc;
        }
    }
    __syncthreads();
    const int ntrip = half ? 80 : 16;
    const int hbase = half ? 16 : 0;
    if (t < ntrip) {
        const float gx = pts[t*3+0] - trans[i*3+0];
        const float gy = pts[t*3+1] - trans[i*3+1];
        const float gz = pts[t*3+2] - trans[i*3+2];
        const float lx = rot[i*9+0]*gx + rot[i*9+3]*gy + rot[i*9+6]*gz;
        const float ly = rot[i*9+1]*gx + rot[i*9+4]*gy + rot[i*9+7]*gz;
        const float lz = rot[i*9+2]*gx + rot[i*9+5]*gy + rot[i*9+8]*gz;
        const int hpv = hbase + t;
        float* catr = cat + (size_t)i*CONCATn;
        catr[192 + hpv] = lx;
        catr[288 + hpv] = ly;
        catr[384 + hpv] = lz;
        catr[480 + hpv] = sqrtf(lx*lx + ly*ly + lz*lz + 1e-8f);
    }
}

// ---------------------------------------------------------------------------
// K6: o_pair = a . z.  Grid (768 i, 2 c-half); thread = (c, head-group of 3).
// ---------------------------------------------------------------------------
__global__ __launch_bounds__(256, 4) void opair_kernel(
    const float* __restrict__ aG, const float* __restrict__ z, float* __restrict__ cat)
{
    const int i = blockIdx.x, half = blockIdx.y, t = threadIdx.x;
    const int c = half*64 + (t & 63);
    const int hg = __builtin_amdgcn_readfirstlane(t >> 6);
    const float* a0 = aG + ((size_t)i*Hn + hg*3)*NN;
    const float* a1 = a0 + NN;
    const float* a2 = a1 + NN;
    const float* zc = z + (size_t)i*NN*CZn + c;
    float x0=0.f, x1=0.f, x2=0.f;
    #pragma unroll 2
    for (int j = 0; j < NN; j += 4) {
        const float4 A0 = *(const float4*)(a0 + j);
        const float4 A1 = *(const float4*)(a1 + j);
        const float4 A2 = *(const float4*)(a2 + j);
        const float z0 = zc[(size_t)(j+0)*CZn];
        const float z1 = zc[(size_t)(j+1)*CZn];
        const float z2 = zc[(size_t)(j+2)*CZn];
        const float z3 = zc[(size_t)(j+3)*CZn];
        x0 += A0.x*z0 + A0.y*z1 + A0.z*z2 + A0.w*z3;
        x1 += A1.x*z0 + A1.y*z1 + A1.z*z2 + A1.w*z3;
        x2 += A2.x*z0 + A2.y*z1 + A2.z*z2 + A2.w*z3;
    }
    float* cr = cat + (size_t)i*CONCATn + 576 + c;
    cr[(size_t)(hg*3+0)*CZn] = x0;
    cr[(size_t)(hg*3+1)*CZn] = x1;
    cr[(size_t)(hg*3+2)*CZn] = x2;
}

// ---------------------------------------------------------------------------
// K7: out = cat @ Wout + bout.  Grid (192, 3), 128 thr.
// ---------------------------------------------------------------------------
__global__ __launch_bounds__(128) void out_kernel(
    const float* __restrict__ cat, const float* __restrict__ Wout,
    const float* __restrict__ bout, float* __restrict__ out)
{
    const int rt = blockIdx.x;
    const int ot = blockIdx.y;
    __shared__ float cl[4 * CONCATn];
    const int r0 = rt * 4;
    const float4* cb = (const float4*)(cat + (size_t)r0 * CONCATn);
    for (int idx = threadIdx.x; idx < CONCATn; idx += 128)
        ((float4*)cl)[idx] = cb[idx];
    __syncthreads();
    const int t = threadIdx.x;
    const int r  = t >> 5;
    const int o4 = t & 31;
    const int col = ot * 128 + o4 * 4;
    float4 acc; acc.x = 0.f; acc.y = 0.f; acc.z = 0.f; acc.w = 0.f;
    const float* wp = Wout + col;
    const float* cr = cl + r * CONCATn;
    #pragma unroll 8
    for (int kk = 0; kk < CONCATn; ++kk) {
        const float4 wv = *(const float4*)(wp + (size_t)kk * 384);
        const float cv = cr[kk];
        acc.x += cv * wv.x; acc.y += cv * wv.y;
        acc.z += cv * wv.z; acc.w += cv * wv.w;
    }
    const float4 bo = *(const float4*)(bout + col);
    acc.x += bo.x; acc.y += bo.y; acc.z += bo.z; acc.w += bo.w;
    *(float4*)(out + (size_t)(r0 + r) * 384 + col) = acc;
}

// ---------------------------------------------------------------------------
extern "C" void kernel_launch(void* const* d_in, const int* in_sizes, int n_in,
                              void* d_out, int out_size, void* d_ws, size_t ws_size,
                              hipStream_t stream)
{
    const float* s     = (const float*)d_in[0];
    const float* z     = (const float*)d_in[1];
    const float* rot   = (const float*)d_in[2];
    const float* trans = (const float*)d_in[3];
    const float* mask  = (const float*)d_in[4];
    const float* Wq    = (const float*)d_in[5];
    const float* bq    = (const float*)d_in[6];
    const float* Wkv   = (const float*)d_in[7];
    const float* bkv   = (const float*)d_in[8];
    const float* Wqp   = (const float*)d_in[9];
    const float* bqp   = (const float*)d_in[10];
    const float* Wkvp  = (const float*)d_in[11];
    const float* bkvp  = (const float*)d_in[12];
    const float* Wb    = (const float*)d_in[13];
    const float* bb    = (const float*)d_in[14];
    const float* head_w= (const float*)d_in[15];
    const float* Wout  = (const float*)d_in[16];
    const float* bout  = (const float*)d_in[17];
    float* out = (float*)d_out;

    float* ws    = (float*)d_ws;
    float* q     = ws;                  // 147456  [N][192]
    float* kT    = q     + 147456;      // 147456  [192][N]
    float* qp    = kT    + 147456;      // 110592  [N][144]
    float* kpT   = qp    + 110592;      // 110592  [144][N]
    float* v     = kpT   + 110592;      // 147456  [N][192]
    float* vp    = v     + 147456;      // 221184  [N][288]
    float* WbT   = vp    + 221184;      // 1536    [12][128]
    float* cat   = WbT   + 1536;        // 1622016
    float* bG    = cat   + 1622016;     // 7077888 (28 MB; also linG during proj)
    float* linG  = bG;                  // overlay: dead before biasg runs
    float* aG    = (ws_size >= (size_t)16664064 * 4) ? (bG + 7077888) : bG;

    hipLaunchKernelGGL(proj_gemm, dim3(48, 18), dim3(256), 0, stream,
        s, Wq, bq, Wkv, bkv, Wqp, bqp, Wkvp, bkvp, linG);
    hipLaunchKernelGGL(scatter_kernel, dim3(768), dim3(256), 0, stream,
        linG, rot, trans, Wb, q, kT, v, qp, kpT, vp, WbT);
    hipLaunchKernelGGL(biasg_kernel, dim3(12, 768), dim3(256), 0, stream,
        z, WbT, bb, bG);
    hipLaunchKernelGGL(lgsm_kernel, dim3(768), dim3(256), 0, stream,
        mask, q, qp, kT, kpT, bG, head_w, aG);
    hipLaunchKernelGGL(opt_kernel, dim3(768, 2), dim3(256), 0, stream,
        aG, v, vp, rot, trans, cat);
    hipLaunchKernelGGL(opair_kernel, dim3(768, 2), dim3(256), 0, stream,
        aG, z, cat);
    hipLaunchKernelGGL(out_kernel, dim3(192, 3), dim3(128), 0, stream,
        cat, Wout, bout, out);
}

// Round 11
// 524.184 us; speedup vs baseline: 1.1458x; 1.1458x over previous
//
#include <hip/hip_runtime.h>
#include <math.h>

#define NN 768
#define CSn 384
#define CZn 128
#define Hn 12
#define CONCATn 2112
#define LGS 772   // LDS attention row stride (772%32=4 -> h-rows hit shifted banks)

// ---------------------------------------------------------------------------
// K1: linG[768][1152] = s @ [Wq|Wkv|Wqp|Wkvp] + bias.  Grid (48 rt, 18 ct).
// ---------------------------------------------------------------------------
__global__ __launch_bounds__(256, 4) void proj_gemm(
    const float* __restrict__ s,
    const float* __restrict__ Wq, const float* __restrict__ bq,
    const float* __restrict__ Wkv, const float* __restrict__ bkv,
    const float* __restrict__ Wqp, const float* __restrict__ bqp,
    const float* __restrict__ Wkvp, const float* __restrict__ bkvp,
    float* __restrict__ linG)
{
    const int rt = blockIdx.x;
    const int ct = blockIdx.y;
    const int t = threadIdx.x;
    const int r0 = rt * 16;
    __shared__ float sl[16 * 388];
    for (int x4 = t; x4 < 1536; x4 += 256) {
        const int r = x4 / 96, c4 = x4 % 96;
        *(float4*)&sl[r * 388 + c4 * 4] = *(const float4*)(s + (size_t)(r0 + r) * CSn + c4 * 4);
    }
    __syncthreads();
    const int c = t & 63, rq = t >> 6;
    const int col = ct * 64 + c;
    const float* Wp; int fout; float bias;
    if (col < 192)      { Wp = Wq + col;         fout = 192; bias = bq[col]; }
    else if (col < 576) { Wp = Wkv + (col-192);  fout = 384; bias = bkv[col-192]; }
    else if (col < 720) { Wp = Wqp + (col-576);  fout = 144; bias = bqp[col-576]; }
    else                { Wp = Wkvp + (col-720); fout = 432; bias = bkvp[col-720]; }
    float a0=bias, a1=bias, a2=bias, a3=bias;
    const float* s0 = sl + (rq*4+0)*388;
    const float* s1 = sl + (rq*4+1)*388;
    const float* s2 = sl + (rq*4+2)*388;
    const float* s3 = sl + (rq*4+3)*388;
    #pragma unroll 4
    for (int kk = 0; kk < 384; ++kk) {
        const float wv = *Wp; Wp += fout;
        a0 += s0[kk]*wv; a1 += s1[kk]*wv; a2 += s2[kk]*wv; a3 += s3[kk]*wv;
    }
    float* lr = linG + (size_t)(r0 + rq*4) * 1152 + col;
    lr[0] = a0; lr[1152] = a1; lr[2*1152] = a2; lr[3*1152] = a3;
}

// ---------------------------------------------------------------------------
// K2: scatter linG -> q [N][192], kT [192][768], v [N][192], qp [N][144],
//     kpT [144][768], vp [N][288]; block 0 builds WbT[12][128].
// ---------------------------------------------------------------------------
__global__ __launch_bounds__(256) void scatter_kernel(
    const float* __restrict__ linG, const float* __restrict__ rot, const float* __restrict__ trans,
    const float* __restrict__ Wb,
    float* __restrict__ q, float* __restrict__ kT, float* __restrict__ v,
    float* __restrict__ qp, float* __restrict__ kpT, float* __restrict__ vp,
    float* __restrict__ WbT)
{
    const int i = blockIdx.x, t = threadIdx.x;
    const float* lr = linG + (size_t)i * 1152;
    if (t < 192) q[(size_t)i*192 + t] = lr[t];
    for (int tt = t; tt < 384; tt += 256) {
        const int h = tt >> 5, cc = tt & 31;
        const float val = lr[192 + tt];
        if (cc < 16) kT[(size_t)(h*16 + cc)*NN + i] = val;
        else         v[(size_t)i*192 + h*16 + (cc-16)] = val;
    }
    const float R0 = rot[i*9+0], R1 = rot[i*9+1], R2 = rot[i*9+2];
    const float R3 = rot[i*9+3], R4 = rot[i*9+4], R5 = rot[i*9+5];
    const float R6 = rot[i*9+6], R7 = rot[i*9+7], R8 = rot[i*9+8];
    const float T0 = trans[i*3+0], T1 = trans[i*3+1], T2 = trans[i*3+2];
    if (t < 48) {
        const float px = lr[576 + t], py = lr[576 + 48 + t], pz = lr[576 + 96 + t];
        float* d = qp + (size_t)i*144 + t*3;
        d[0] = R0*px + R1*py + R2*pz + T0;
        d[1] = R3*px + R4*py + R5*pz + T1;
        d[2] = R6*px + R7*py + R8*pz + T2;
    }
    if (t < 144) {
        const float px = lr[720 + t], py = lr[720 + 144 + t], pz = lr[720 + 288 + t];
        const float gx = R0*px + R1*py + R2*pz + T0;
        const float gy = R3*px + R4*py + R5*pz + T1;
        const float gz = R6*px + R7*py + R8*pz + T2;
        const int h = t / 12, pp = t % 12;
        if (pp < 4) {
            float* d = kpT + (size_t)(h*12 + pp*3)*NN + i;
            d[0] = gx; d[NN] = gy; d[2*NN] = gz;
        } else {
            float* d = vp + (size_t)i*288 + ((h*8) + (pp-4))*3;
            d[0] = gx; d[1] = gy; d[2] = gz;
        }
    }
    if (i == 0) for (int x = t; x < 1536; x += 256) WbT[x] = Wb[(x & 127)*12 + (x >> 7)];
}

// ---------------------------------------------------------------------------
// K3: biasg v2 = S_B*(z@Wb + bb) -> bG[i][h][j].  Grid (12 jt, 768 i).
// All 8 z float4 loads issued UP-FRONT (independent, in flight together);
// WbT staged in LDS (broadcast ds_reads, no dependent global loads).
// ---------------------------------------------------------------------------
__global__ __launch_bounds__(256, 4) void biasg_kernel(
    const float* __restrict__ z, const float* __restrict__ WbT,
    const float* __restrict__ bb, float* __restrict__ bG)
{
    const int jt = blockIdx.x, i = blockIdx.y, t = threadIdx.x;
    __shared__ float wbs[1536];   // 6 KB: WbT[12][128]
    for (int x = t; x < 1536; x += 256) wbs[x] = WbT[x];
    __syncthreads();

    const int jl = t >> 2, g = t & 3;
    const int j = jt * 64 + jl;
    const float* zr = z + ((size_t)i * NN + j) * CZn + g * 4;
    float4 zv[8];
    #pragma unroll
    for (int u = 0; u < 8; ++u) zv[u] = *(const float4*)(zr + u * 16);   // 8 in flight

    float bh[12];
    #pragma unroll
    for (int h = 0; h < 12; ++h) bh[h] = 0.f;
    #pragma unroll
    for (int u = 0; u < 8; ++u) {
        const float* wb = wbs + u*16 + g*4;
        #pragma unroll
        for (int h = 0; h < 12; ++h) {
            const float4 wv = *(const float4*)(wb + h * 128);   // LDS b128 broadcast
            bh[h] += zv[u].x*wv.x + zv[u].y*wv.y + zv[u].z*wv.z + zv[u].w*wv.w;
        }
    }
    #pragma unroll
    for (int h = 0; h < 12; ++h) {
        bh[h] += __shfl_xor(bh[h], 1);
        bh[h] += __shfl_xor(bh[h], 2);
    }
    float bsel[3];
    #pragma unroll
    for (int hh = 0; hh < 3; ++hh) {
        const float v01 = (g & 1) ? bh[3+hh] : bh[0+hh];
        const float v23 = (g & 1) ? bh[9+hh] : bh[6+hh];
        bsel[hh] = (g & 2) ? v23 : v01;
    }
    float* bgr = bG + (size_t)i * (Hn*NN) + j;
    #pragma unroll
    for (int hh = 0; hh < 3; ++hh) {
        const int h = 3*g + hh;
        bgr[(size_t)h * NN] = 0.5773502691896258f * (bsel[hh] + bb[h]);
    }
}

// ---------------------------------------------------------------------------
// K4: MEGA per-i kernel: logits+softmax (a -> LDS) -> o/o_pt -> norms ->
//     o_pair.  Grid (768).  a never round-trips through global.
// ---------------------------------------------------------------------------
__global__ __launch_bounds__(256, 3) void mega_kernel(
    const float* __restrict__ mask,
    const float* __restrict__ q, const float* __restrict__ qp,
    const float* __restrict__ kT, const float* __restrict__ kpT,
    const float* __restrict__ bG, const float* __restrict__ head_w,
    const float* __restrict__ z,
    const float* __restrict__ v, const float* __restrict__ vp,
    const float* __restrict__ rot, const float* __restrict__ trans,
    float* __restrict__ cat)
{
    const int i = blockIdx.x, t = threadIdx.x;
    const int w = t >> 6, l = t & 63;
    __shared__ float lg[Hn * LGS];     // 37 KB attention
    __shared__ float qs[192], qps[144], coefS[12];
    __shared__ float pts[288];
    if (t < 192) qs[t] = q[(size_t)i*192 + t];
    if (t < 144) qps[t] = qp[(size_t)i*144 + t];
    if (t < 12) coefS[t] = -0.5f * 0.1360827634879543f * log1pf(expf(head_w[t]));
    __syncthreads();
    const float mi = mask[i];

    // ---- Phase 1: logits + softmax (wave w owns heads 3w..3w+2) ----------
    #pragma unroll 1
    for (int hh = 0; hh < 3; ++hh) {
        const int h = w*3 + hh;
        float qreg[16], qpreg[12];
        #pragma unroll
        for (int c = 0; c < 16; ++c) qreg[c] = qs[h*16 + c];
        #pragma unroll
        for (int e = 0; e < 12; ++e) qpreg[e] = qps[h*12 + e];
        const float coef = coefS[h];
        const float* kb  = kT  + (size_t)(h*16)*NN + l;
        const float* kpb = kpT + (size_t)(h*12)*NN + l;
        const float* bgb = bG + (size_t)i*(Hn*NN) + (size_t)h*NN + l;
        float e[12];
        #pragma unroll
        for (int u = 0; u < 12; ++u) {
            const int jo = u * 64;
            float qk = 0.f;
            #pragma unroll
            for (int c = 0; c < 16; ++c) qk += qreg[c] * kb[(size_t)c*NN + jo];
            float d2s = 0.f;
            #pragma unroll
            for (int ee = 0; ee < 12; ++ee) {
                const float d = qpreg[ee] - kpb[(size_t)ee*NN + jo];
                d2s += d * d;
            }
            const float mterm = 100000.0f * (mi * mask[l + jo] - 1.0f);
            e[u] = 0.14433756729740643f*qk + bgb[jo] + coef*d2s + mterm;
        }
        float m = -1e30f;
        #pragma unroll
        for (int u = 0; u < 12; ++u) m = fmaxf(m, e[u]);
        #pragma unroll
        for (int off = 32; off > 0; off >>= 1) m = fmaxf(m, __shfl_xor(m, off));
        float ssum = 0.f;
        #pragma unroll
        for (int u = 0; u < 12; ++u) { e[u] = expf(e[u] - m); ssum += e[u]; }
        #pragma unroll
        for (int off = 32; off > 0; off >>= 1) ssum += __shfl_xor(ssum, off);
        const float inv = 1.0f / ssum;
        #pragma unroll
        for (int u = 0; u < 12; ++u) lg[h*LGS + l + u*64] = e[u] * inv;
    }
    __syncthreads();

    // ---- Phase 2: o (192) + o_pt (288), column-coalesced src reads -------
    {
        float accA = 0.f;
        const float* srcA; int strA; int hA;
        if (t < 192) { srcA = v + t;          strA = 192; hA = t >> 4; }
        else         { srcA = vp + (t - 192); strA = 288; hA = (t - 192) / 24; }
        const float* arA = lg + hA * LGS;
        #pragma unroll 8
        for (int j = 0; j < NN; ++j) accA += arA[j] * srcA[(size_t)j * strA];

        float accB = 0.f;
        const int cB = 64 + t;                 // vp cols 64..287 (t<224)
        const float* srcB = vp + cB;
        const float* arB = lg + (cB / 24) * LGS;
        if (t < 224) {
            #pragma unroll 8
            for (int j = 0; j < NN; ++j) accB += arB[j] * srcB[(size_t)j * 288];
        }
        float* catr = cat + (size_t)i*CONCATn;
        if (t < 192) catr[t] = accA;
        else         pts[t - 192] = accA;
        if (t < 224) pts[64 + t] = accB;
    }
    __syncthreads();

    // ---- Phase 3: frame invert + norms -----------------------------------
    if (t < 96) {
        const float gx = pts[t*3+0] - trans[i*3+0];
        const float gy = pts[t*3+1] - trans[i*3+1];
        const float gz = pts[t*3+2] - trans[i*3+2];
        const float lx = rot[i*9+0]*gx + rot[i*9+3]*gy + rot[i*9+6]*gz;
        const float ly = rot[i*9+1]*gx + rot[i*9+4]*gy + rot[i*9+7]*gz;
        const float lz = rot[i*9+2]*gx + rot[i*9+5]*gy + rot[i*9+8]*gz;
        float* catr = cat + (size_t)i*CONCATn;
        catr[192 + t] = lx;
        catr[288 + t] = ly;
        catr[384 + t] = lz;
        catr[480 + t] = sqrtf(lx*lx + ly*ly + lz*lz + 1e-8f);
    }

    // ---- Phase 4: o_pair = a . z  (wave w: heads 3w..3w+2; float2/lane) --
    {
        const float* zi = z + (size_t)i*NN*CZn + 2*l;
        const float* a0 = lg + (size_t)(3*w + 0)*LGS;
        const float* a1 = lg + (size_t)(3*w + 1)*LGS;
        const float* a2 = lg + (size_t)(3*w + 2)*LGS;
        float x0a=0.f, x0b=0.f, x1a=0.f, x1b=0.f, x2a=0.f, x2b=0.f;
        #pragma unroll 8
        for (int j = 0; j < NN; ++j) {
            const float2 zv = *(const float2*)(zi + (size_t)j*CZn);
            const float A0 = a0[j], A1 = a1[j], A2 = a2[j];   // LDS broadcast
            x0a += A0*zv.x; x0b += A0*zv.y;
            x1a += A1*zv.x; x1b += A1*zv.y;
            x2a += A2*zv.x; x2b += A2*zv.y;
        }
        float* cr = cat + (size_t)i*CONCATn + 576 + 2*l;
        cr[(size_t)(3*w+0)*CZn + 0] = x0a; cr[(size_t)(3*w+0)*CZn + 1] = x0b;
        cr[(size_t)(3*w+1)*CZn + 0] = x1a; cr[(size_t)(3*w+1)*CZn + 1] = x1b;
        cr[(size_t)(3*w+2)*CZn + 0] = x2a; cr[(size_t)(3*w+2)*CZn + 1] = x2b;
    }
}

// ---------------------------------------------------------------------------
// K5: out = cat @ Wout + bout.  Grid (192, 3), 128 thr.
// ---------------------------------------------------------------------------
__global__ __launch_bounds__(128) void out_kernel(
    const float* __restrict__ cat, const float* __restrict__ Wout,
    const float* __restrict__ bout, float* __restrict__ out)
{
    const int rt = blockIdx.x;
    const int ot = blockIdx.y;
    __shared__ float cl[4 * CONCATn];
    const int r0 = rt * 4;
    const float4* cb = (const float4*)(cat + (size_t)r0 * CONCATn);
    for (int idx = threadIdx.x; idx < CONCATn; idx += 128)
        ((float4*)cl)[idx] = cb[idx];
    __syncthreads();
    const int t = threadIdx.x;
    const int r  = t >> 5;
    const int o4 = t & 31;
    const int col = ot * 128 + o4 * 4;
    float4 acc; acc.x = 0.f; acc.y = 0.f; acc.z = 0.f; acc.w = 0.f;
    const float* wp = Wout + col;
    const float* cr = cl + r * CONCATn;
    #pragma unroll 8
    for (int kk = 0; kk < CONCATn; ++kk) {
        const float4 wv = *(const float4*)(wp + (size_t)kk * 384);
        const float cv = cr[kk];
        acc.x += cv * wv.x; acc.y += cv * wv.y;
        acc.z += cv * wv.z; acc.w += cv * wv.w;
    }
    const float4 bo = *(const float4*)(bout + col);
    acc.x += bo.x; acc.y += bo.y; acc.z += bo.z; acc.w += bo.w;
    *(float4*)(out + (size_t)(r0 + r) * 384 + col) = acc;
}

// ---------------------------------------------------------------------------
extern "C" void kernel_launch(void* const* d_in, const int* in_sizes, int n_in,
                              void* d_out, int out_size, void* d_ws, size_t ws_size,
                              hipStream_t stream)
{
    const float* s     = (const float*)d_in[0];
    const float* z     = (const float*)d_in[1];
    const float* rot   = (const float*)d_in[2];
    const float* trans = (const float*)d_in[3];
    const float* mask  = (const float*)d_in[4];
    const float* Wq    = (const float*)d_in[5];
    const float* bq    = (const float*)d_in[6];
    const float* Wkv   = (const float*)d_in[7];
    const float* bkv   = (const float*)d_in[8];
    const float* Wqp   = (const float*)d_in[9];
    const float* bqp   = (const float*)d_in[10];
    const float* Wkvp  = (const float*)d_in[11];
    const float* bkvp  = (const float*)d_in[12];
    const float* Wb    = (const float*)d_in[13];
    const float* bb    = (const float*)d_in[14];
    const float* head_w= (const float*)d_in[15];
    const float* Wout  = (const float*)d_in[16];
    const float* bout  = (const float*)d_in[17];
    float* out = (float*)d_out;

    float* ws    = (float*)d_ws;
    float* q     = ws;                  // 147456  [N][192]
    float* kT    = q     + 147456;      // 147456  [192][N]
    float* qp    = kT    + 147456;      // 110592  [N][144]
    float* kpT   = qp    + 110592;      // 110592  [144][N]
    float* v     = kpT   + 110592;      // 147456  [N][192]
    float* vp    = v     + 147456;      // 221184  [N][288]
    float* WbT   = vp    + 221184;      // 1536    [12][128]
    float* cat   = WbT   + 1536;        // 1622016
    float* bG    = cat   + 1622016;     // 7077888 (28 MB; overlaid with linG)
    float* linG  = bG;                  // dead before biasg runs

    hipLaunchKernelGGL(proj_gemm, dim3(48, 18), dim3(256), 0, stream,
        s, Wq, bq, Wkv, bkv, Wqp, bqp, Wkvp, bkvp, linG);
    hipLaunchKernelGGL(scatter_kernel, dim3(768), dim3(256), 0, stream,
        linG, rot, trans, Wb, q, kT, v, qp, kpT, vp, WbT);
    hipLaunchKernelGGL(biasg_kernel, dim3(12, 768), dim3(256), 0, stream,
        z, WbT, bb, bG);
    hipLaunchKernelGGL(mega_kernel, dim3(768), dim3(256), 0, stream,
        mask, q, qp, kT, kpT, bG, head_w, z, v, vp, rot, trans, cat);
    hipLaunchKernelGGL(out_kernel, dim3(192, 3), dim3(128), 0, stream,
        cat, Wout, bout, out);
}